// Round 6
// baseline (134.246 us; speedup 1.0000x reference)
//
#include <hip/hip_runtime.h>
#include <hip/hip_bf16.h>

#define A_TOT 32
#define SEQ 1024
#define DIM 64

typedef __attribute__((ext_vector_type(8))) short short8;
typedef __attribute__((ext_vector_type(4))) float f32x4;

static __device__ __forceinline__ unsigned pack2bf(float a, float b) {
    union { __hip_bfloat16 h[2]; unsigned u; } x;
    x.h[0] = __float2bfloat16(a);
    x.h[1] = __float2bfloat16(b);
    return x.u;
}

// ---------------- cast fp32 -> bf16 ----------------
__global__ void cast_bf16_kernel(const float* __restrict__ src,
                                 __hip_bfloat16* __restrict__ dst, int n) {
    int i = (blockIdx.x * blockDim.x + threadIdx.x) * 4;
    if (i >= n) return;
    float4 f = *reinterpret_cast<const float4*>(src + i);
    union { __hip_bfloat16 h[4]; ushort4 u; } cv;
    cv.h[0] = __float2bfloat16(f.x);
    cv.h[1] = __float2bfloat16(f.y);
    cv.h[2] = __float2bfloat16(f.z);
    cv.h[3] = __float2bfloat16(f.w);
    *reinterpret_cast<ushort4*>(dst + i) = cv.u;
}

// ---------------- transpose+cast v [bh][n][d] -> vt [bh][d][n] ----------------
__global__ void transpose_v_kernel(const float* __restrict__ v,
                                   __hip_bfloat16* __restrict__ vt) {
    __shared__ __hip_bfloat16 tile[64][65];
    int bh = blockIdx.y;
    int n0 = blockIdx.x * 64;
    const float* vsrc = v + ((size_t)bh * SEQ + n0) * DIM;
    for (int e = threadIdx.x; e < 64 * 64; e += 256) {
        int i = e >> 6;
        int d = e & 63;
        tile[i][d] = __float2bfloat16(vsrc[(size_t)i * DIM + d]);
    }
    __syncthreads();
    __hip_bfloat16* vdst = vt + (size_t)bh * DIM * SEQ + n0;
    for (int e = threadIdx.x; e < 64 * 64; e += 256) {
        int d = e >> 6;
        int i = e & 63;
        vdst[(size_t)d * SEQ + i] = tile[i][d];
    }
}

// ---------------- fused masked attention, split-KV, phase-split ----------------
// grid: (64 row-blocks of 16 rows, 32 bh), block 256 (4 waves).
// Wave w owns rows [rb*16,+16) x KV cols [w*256,+256).
// Phase A: all 16 QK chains (no LDS, no clobbers) -> deep load pipelining.
// Phase B: row-sum stats. Phase C: PV with per-tile LDS transpose + V dbuf.
// Phase D: attn writes from regs + O combine.
__launch_bounds__(256, 4)
__global__ void graph_attn_kernel(const __hip_bfloat16* __restrict__ qb,
                                  const __hip_bfloat16* __restrict__ kb,
                                  const __hip_bfloat16* __restrict__ vt,
                                  const int* __restrict__ adj,
                                  float* __restrict__ out,    // [32,1024,64]
                                  float* __restrict__ attn) { // [32,1024,1024]
    __shared__ unsigned plds_u[4][16][36]; // per-wave per-tile p staging (9216 B)
    __shared__ float olds[4][16][68];      // O partial combine (17408 B)
    __shared__ float part[4][4][16];       // per-wave per-lgi row partials
    __shared__ float lsum_sh[4][16];       // per-wave row sums

    const int bh    = blockIdx.y;
    const int rb    = blockIdx.x;
    const int batch = bh & 3;           // a_idx = h*4 + batch
    const int tid   = threadIdx.x;
    const int wid   = tid >> 6;
    const int lane  = tid & 63;
    const int lr    = lane & 15;        // query row within the 16-row tile
    const int lgi   = lane >> 4;        // k-group / reg-group
    const int row16 = rb * 16;
    const int kvbase = wid * 256;

    // Q fragments: lane holds Q[row16+lr][lgi*8 .. +8) per 32-wide k-step
    const __hip_bfloat16* qrow = qb + ((size_t)bh * SEQ + row16 + lr) * DIM + lgi * 8;
    const short8 qf0 = *reinterpret_cast<const short8*>(qrow);
    const short8 qf1 = *reinterpret_cast<const short8*>(qrow + 32);

    const int* adjrow = adj + (size_t)batch * SEQ * SEQ + (size_t)(row16 + lr) * SEQ;
    const __hip_bfloat16* kbh = kb + (size_t)bh * SEQ * DIM;

    float lp = 0.f;         // lane partial sum of exp over its owned columns
    unsigned p_pk[4][4][2]; // packed unnormalized p: [t][c][pair]

    // ---- Phase A: S = K.Q^T (swapped), p_un = exp -> regs. 16 indep chains ----
#pragma unroll
    for (int t = 0; t < 4; ++t) {
        const int n0 = kvbase + t * 64;
#pragma unroll
        for (int c = 0; c < 4; ++c) {
            const __hip_bfloat16* krow = kbh + (size_t)(n0 + c * 16 + lr) * DIM + lgi * 8;
            short8 kf0 = *reinterpret_cast<const short8*>(krow);
            short8 kf1 = *reinterpret_cast<const short8*>(krow + 32);
            f32x4 acc = {0.f, 0.f, 0.f, 0.f};
            acc = __builtin_amdgcn_mfma_f32_16x16x32_bf16(kf0, qf0, acc, 0, 0, 0);
            acc = __builtin_amdgcn_mfma_f32_16x16x32_bf16(kf1, qf1, acc, 0, 0, 0);
            // acc[j] = S[q=row16+lr][kv = n0 + c*16 + lgi*4 + j]
            const int4 av = *reinterpret_cast<const int4*>(adjrow + n0 + c * 16 + lgi * 4);
            float p0 = (av.x > 0) ? __expf(acc[0] * 0.125f) : 0.f;
            float p1 = (av.y > 0) ? __expf(acc[1] * 0.125f) : 0.f;
            float p2 = (av.z > 0) ? __expf(acc[2] * 0.125f) : 0.f;
            float p3 = (av.w > 0) ? __expf(acc[3] * 0.125f) : 0.f;
            lp += (p0 + p1) + (p2 + p3);
            p_pk[t][c][0] = pack2bf(p0, p1);
            p_pk[t][c][1] = pack2bf(p2, p3);
        }
    }

    // ---- Phase B: wave-local row sums via LDS, then cross-wave combine ----
    part[wid][lgi][lr] = lp;
    asm volatile("" ::: "memory");
    if (lane < 16) {
        lsum_sh[wid][lane] = part[wid][0][lane] + part[wid][1][lane] +
                             part[wid][2][lane] + part[wid][3][lane];
    }
    __syncthreads();

    float ltot[4];
#pragma unroll
    for (int j = 0; j < 4; ++j) {
        const int row = lgi * 4 + j;
        float s = lsum_sh[0][row] + lsum_sh[1][row] + lsum_sh[2][row] + lsum_sh[3][row];
        ltot[j] = 1.0f / (s + 1e-37f);
    }
    float lrt = lsum_sh[0][lr] + lsum_sh[1][lr] + lsum_sh[2][lr] + lsum_sh[3][lr];
    const float linv_r = 1.0f / (lrt + 1e-37f);

    // ---- Phase C: PV via per-tile LDS transpose; V double-buffered ----
    f32x4 o[4];
#pragma unroll
    for (int c = 0; c < 4; ++c) o[c] = (f32x4){0.f, 0.f, 0.f, 0.f};

    short8 vf[2][4][2];
#pragma unroll
    for (int c2 = 0; c2 < 4; ++c2) {
        const __hip_bfloat16* vrow =
            vt + ((size_t)bh * DIM + c2 * 16 + lr) * SEQ + kvbase + lgi * 8;
        vf[0][c2][0] = *reinterpret_cast<const short8*>(vrow);
        vf[0][c2][1] = *reinterpret_cast<const short8*>(vrow + 32);
    }

#pragma unroll
    for (int t = 0; t < 4; ++t) {
        const int cur = t & 1, nxt = cur ^ 1;
        // stage tile t's p into LDS (uint stores; same type as reads below)
#pragma unroll
        for (int c = 0; c < 4; ++c) {
            plds_u[wid][lr][c * 8 + lgi * 2 + 0] = p_pk[t][c][0];
            plds_u[wid][lr][c * 8 + lgi * 2 + 1] = p_pk[t][c][1];
        }
        // prefetch next tile's V before the ordering clobber
        if (t < 3) {
            const int n1 = kvbase + (t + 1) * 64;
#pragma unroll
            for (int c2 = 0; c2 < 4; ++c2) {
                const __hip_bfloat16* vrow =
                    vt + ((size_t)bh * DIM + c2 * 16 + lr) * SEQ + n1 + lgi * 8;
                vf[nxt][c2][0] = *reinterpret_cast<const short8*>(vrow);
                vf[nxt][c2][1] = *reinterpret_cast<const short8*>(vrow + 32);
            }
        }
        asm volatile("" ::: "memory");
        // P fragments (A operand): lane lr holds P[row lr][kv-local lgi*8..]
        short8 pf0 = *reinterpret_cast<const short8*>(&plds_u[wid][lr][lgi * 4]);
        short8 pf1 = *reinterpret_cast<const short8*>(&plds_u[wid][lr][16 + lgi * 4]);
        asm volatile("" ::: "memory");
#pragma unroll
        for (int c2 = 0; c2 < 4; ++c2) {
            o[c2] = __builtin_amdgcn_mfma_f32_16x16x32_bf16(pf0, vf[cur][c2][0], o[c2], 0, 0, 0);
            o[c2] = __builtin_amdgcn_mfma_f32_16x16x32_bf16(pf1, vf[cur][c2][1], o[c2], 0, 0, 0);
        }
    }

    // ---- Phase D: attn writes (normalized, unpacked from regs) ----
    float* attn_row = attn + (size_t)bh * SEQ * SEQ + (size_t)(row16 + lr) * SEQ;
#pragma unroll
    for (int t = 0; t < 4; ++t) {
#pragma unroll
        for (int c = 0; c < 4; ++c) {
            const unsigned u01 = p_pk[t][c][0];
            const unsigned u23 = p_pk[t][c][1];
            float f0 = __uint_as_float(u01 << 16) * linv_r;
            float f1 = __uint_as_float(u01 & 0xffff0000u) * linv_r;
            float f2 = __uint_as_float(u23 << 16) * linv_r;
            float f3 = __uint_as_float(u23 & 0xffff0000u) * linv_r;
            *reinterpret_cast<float4*>(attn_row + kvbase + t * 64 + c * 16 + lgi * 4) =
                (float4){f0, f1, f2, f3};
        }
    }

    // ---- scale O partials, combine across waves ----
#pragma unroll
    for (int c2 = 0; c2 < 4; ++c2)
#pragma unroll
        for (int j = 0; j < 4; ++j)
            olds[wid][lgi * 4 + j][c2 * 16 + lr] = o[c2][j] * ltot[j];
    __syncthreads();

    const int r  = tid >> 4;  // 0..15
    const int c4 = tid & 15;  // 0..15 (float4 column)
    float s0 = 0.f, s1 = 0.f, s2 = 0.f, s3 = 0.f;
#pragma unroll
    for (int w = 0; w < 4; ++w) {
        s0 += olds[w][r][c4 * 4 + 0];
        s1 += olds[w][r][c4 * 4 + 1];
        s2 += olds[w][r][c4 * 4 + 2];
        s3 += olds[w][r][c4 * 4 + 3];
    }
    float* ob = out + (size_t)bh * SEQ * DIM + (size_t)(row16 + r) * DIM + c4 * 4;
    *reinterpret_cast<float4*>(ob) = (float4){s0, s1, s2, s3};
}

extern "C" void kernel_launch(void* const* d_in, const int* in_sizes, int n_in,
                              void* d_out, int out_size, void* d_ws, size_t ws_size,
                              hipStream_t stream) {
    const float* q   = (const float*)d_in[0];
    const float* k   = (const float*)d_in[1];
    const float* v   = (const float*)d_in[2];
    const int*   adj = (const int*)d_in[3];

    float* out  = (float*)d_out;                   // [32,1024,64]
    float* attn = out + (size_t)A_TOT * SEQ * DIM; // [32,1024,1024]

    __hip_bfloat16* qb = (__hip_bfloat16*)d_ws;
    __hip_bfloat16* kb = qb + (size_t)A_TOT * SEQ * DIM;
    __hip_bfloat16* vt = kb + (size_t)A_TOT * SEQ * DIM;

    const int n = A_TOT * SEQ * DIM;  // 2,097,152
    cast_bf16_kernel<<<n / (4 * 256), 256, 0, stream>>>(q, qb, n);
    cast_bf16_kernel<<<n / (4 * 256), 256, 0, stream>>>(k, kb, n);
    transpose_v_kernel<<<dim3(SEQ / 64, A_TOT), 256, 0, stream>>>(v, vt);
    graph_attn_kernel<<<dim3(SEQ / 16, A_TOT), 256, 0, stream>>>(qb, kb, vt, adj, out, attn);
}

// Round 7
// 108.095 us; speedup vs baseline: 1.2419x; 1.2419x over previous
//
#include <hip/hip_runtime.h>
#include <hip/hip_bf16.h>

#define A_TOT 32
#define SEQ 1024
#define DIM 64

typedef __attribute__((ext_vector_type(8))) short short8;
typedef __attribute__((ext_vector_type(4))) float f32x4;

static __device__ __forceinline__ unsigned pack2bf(float a, float b) {
    union { __hip_bfloat16 h[2]; unsigned u; } x;
    x.h[0] = __float2bfloat16(a);
    x.h[1] = __float2bfloat16(b);
    return x.u;
}

// ---------------- cast fp32 -> bf16 ----------------
__global__ void cast_bf16_kernel(const float* __restrict__ src,
                                 __hip_bfloat16* __restrict__ dst, int n) {
    int i = (blockIdx.x * blockDim.x + threadIdx.x) * 4;
    if (i >= n) return;
    float4 f = *reinterpret_cast<const float4*>(src + i);
    union { __hip_bfloat16 h[4]; ushort4 u; } cv;
    cv.h[0] = __float2bfloat16(f.x);
    cv.h[1] = __float2bfloat16(f.y);
    cv.h[2] = __float2bfloat16(f.z);
    cv.h[3] = __float2bfloat16(f.w);
    *reinterpret_cast<ushort4*>(dst + i) = cv.u;
}

// ---------------- transpose+cast v [bh][n][d] -> vt [bh][d][n] ----------------
__global__ void transpose_v_kernel(const float* __restrict__ v,
                                   __hip_bfloat16* __restrict__ vt) {
    __shared__ __hip_bfloat16 tile[64][65];
    int bh = blockIdx.y;
    int n0 = blockIdx.x * 64;
    const float* vsrc = v + ((size_t)bh * SEQ + n0) * DIM;
    for (int e = threadIdx.x; e < 64 * 64; e += 256) {
        int i = e >> 6;
        int d = e & 63;
        tile[i][d] = __float2bfloat16(vsrc[(size_t)i * DIM + d]);
    }
    __syncthreads();
    __hip_bfloat16* vdst = vt + (size_t)bh * DIM * SEQ + n0;
    for (int e = threadIdx.x; e < 64 * 64; e += 256) {
        int d = e >> 6;
        int i = e & 63;
        vdst[(size_t)d * SEQ + i] = tile[i][d];
    }
}

// ---------------- fused masked attention, split-KV, K-permuted ----------------
// grid: (64 row-blocks of 16 rows, 32 bh), block 256 (4 waves).
// Wave w owns rows [rb*16,+16) x KV cols [w*256,+256).
// K rows are loaded in a permuted order chosen so the QK^T (swapped,
// mfma(K,Q)) output lands DIRECTLY in PV A-fragment ownership:
//   c-iter c: loader lane reads K row n0+(c>>1)*32+(lr>>2)*8+(c&1)*4+(lr&3)
//   => acc[j] at lane (lgi,lr) = S[lr][n0+(c>>1)*32+lgi*8+(c&1)*4+j]
// PV fragments are then pure register concats of p_pk — no LDS staging,
// no memory clobbers in the hot loops, full compiler pipelining.
__launch_bounds__(256)
__global__ void graph_attn_kernel(const __hip_bfloat16* __restrict__ qb,
                                  const __hip_bfloat16* __restrict__ kb,
                                  const __hip_bfloat16* __restrict__ vt,
                                  const int* __restrict__ adj,
                                  float* __restrict__ out,    // [32,1024,64]
                                  float* __restrict__ attn) { // [32,1024,1024]
    __shared__ float olds[4][16][68];      // O partial combine (17408 B)
    __shared__ float part[4][4][16];       // per-wave per-lgi row partials
    __shared__ float lsum_sh[4][16];       // per-wave row sums

    const int bh    = blockIdx.y;
    const int rb    = blockIdx.x;
    const int batch = bh & 3;           // a_idx = h*4 + batch
    const int tid   = threadIdx.x;
    const int wid   = tid >> 6;
    const int lane  = tid & 63;
    const int lr    = lane & 15;        // query row within the 16-row tile
    const int lgi   = lane >> 4;        // k-group / reg-group
    const int row16 = rb * 16;
    const int kvbase = wid * 256;

    // Q fragments: lane holds Q[row16+lr][lgi*8 .. +8) per 32-wide k-step
    const __hip_bfloat16* qrow = qb + ((size_t)bh * SEQ + row16 + lr) * DIM + lgi * 8;
    const short8 qf0 = *reinterpret_cast<const short8*>(qrow);
    const short8 qf1 = *reinterpret_cast<const short8*>(qrow + 32);

    const int* adjrow = adj + (size_t)batch * SEQ * SEQ + (size_t)(row16 + lr) * SEQ;
    const __hip_bfloat16* kbh = kb + (size_t)bh * SEQ * DIM;

    // loader-role row permutation constant for this lane
    const int kperm = (lr >> 2) * 8 + (lr & 3);

    float lp = 0.f;         // lane partial sum of exp over its owned columns
    unsigned p_pk[4][4][2]; // packed unnormalized p: [t][c][pair]

    // ---- Phase A: S = K.Q^T (swapped, K-permuted), p_un = exp -> regs ----
#pragma unroll
    for (int t = 0; t < 4; ++t) {
        const int n0 = kvbase + t * 64;
#pragma unroll
        for (int c = 0; c < 4; ++c) {
            const int colbase = (c >> 1) * 32 + (c & 1) * 4;  // + lgi*8 => lane cols
            const __hip_bfloat16* krow =
                kbh + (size_t)(n0 + colbase + kperm) * DIM + lgi * 8;
            short8 kf0 = *reinterpret_cast<const short8*>(krow);
            short8 kf1 = *reinterpret_cast<const short8*>(krow + 32);
            f32x4 acc = {0.f, 0.f, 0.f, 0.f};
            acc = __builtin_amdgcn_mfma_f32_16x16x32_bf16(kf0, qf0, acc, 0, 0, 0);
            acc = __builtin_amdgcn_mfma_f32_16x16x32_bf16(kf1, qf1, acc, 0, 0, 0);
            // acc[j] = S[q=row16+lr][kv = n0 + colbase + lgi*8 + j]
            const int4 av = *reinterpret_cast<const int4*>(adjrow + n0 + colbase + lgi * 8);
            float p0 = (av.x > 0) ? __expf(acc[0] * 0.125f) : 0.f;
            float p1 = (av.y > 0) ? __expf(acc[1] * 0.125f) : 0.f;
            float p2 = (av.z > 0) ? __expf(acc[2] * 0.125f) : 0.f;
            float p3 = (av.w > 0) ? __expf(acc[3] * 0.125f) : 0.f;
            lp += (p0 + p1) + (p2 + p3);
            p_pk[t][c][0] = pack2bf(p0, p1);
            p_pk[t][c][1] = pack2bf(p2, p3);
        }
    }

    // ---- Phase B: wave-local row sums via LDS, then cross-wave combine ----
    part[wid][lgi][lr] = lp;
    asm volatile("" ::: "memory");
    if (lane < 16) {
        lsum_sh[wid][lane] = part[wid][0][lane] + part[wid][1][lane] +
                             part[wid][2][lane] + part[wid][3][lane];
    }
    __syncthreads();

    float ltot[4];
#pragma unroll
    for (int j = 0; j < 4; ++j) {
        const int row = lgi * 4 + j;
        float s = lsum_sh[0][row] + lsum_sh[1][row] + lsum_sh[2][row] + lsum_sh[3][row];
        ltot[j] = 1.0f / (s + 1e-37f);
    }
    float lrt = lsum_sh[0][lr] + lsum_sh[1][lr] + lsum_sh[2][lr] + lsum_sh[3][lr];
    const float linv_r = 1.0f / (lrt + 1e-37f);

    // ---- Phase C: PV — fragments are in-register concats; V single-buffered ----
    f32x4 o[4];
#pragma unroll
    for (int c = 0; c < 4; ++c) o[c] = (f32x4){0.f, 0.f, 0.f, 0.f};

#pragma unroll
    for (int t = 0; t < 4; ++t) {
        const int n0 = kvbase + t * 64;
        union { unsigned u[4]; short8 s; } pf0, pf1;
        pf0.u[0] = p_pk[t][0][0]; pf0.u[1] = p_pk[t][0][1];
        pf0.u[2] = p_pk[t][1][0]; pf0.u[3] = p_pk[t][1][1];
        pf1.u[0] = p_pk[t][2][0]; pf1.u[1] = p_pk[t][2][1];
        pf1.u[2] = p_pk[t][3][0]; pf1.u[3] = p_pk[t][3][1];
#pragma unroll
        for (int c2 = 0; c2 < 4; ++c2) {
            const __hip_bfloat16* vrow =
                vt + ((size_t)bh * DIM + c2 * 16 + lr) * SEQ + n0 + lgi * 8;
            short8 vf0 = *reinterpret_cast<const short8*>(vrow);
            short8 vf1 = *reinterpret_cast<const short8*>(vrow + 32);
            o[c2] = __builtin_amdgcn_mfma_f32_16x16x32_bf16(pf0.s, vf0, o[c2], 0, 0, 0);
            o[c2] = __builtin_amdgcn_mfma_f32_16x16x32_bf16(pf1.s, vf1, o[c2], 0, 0, 0);
        }
    }

    // ---- Phase D: attn writes (normalized, unpacked from regs) ----
    float* attn_row = attn + (size_t)bh * SEQ * SEQ + (size_t)(row16 + lr) * SEQ;
#pragma unroll
    for (int t = 0; t < 4; ++t) {
#pragma unroll
        for (int c = 0; c < 4; ++c) {
            const int colbase = (c >> 1) * 32 + (c & 1) * 4;
            const unsigned u01 = p_pk[t][c][0];
            const unsigned u23 = p_pk[t][c][1];
            float f0 = __uint_as_float(u01 << 16) * linv_r;
            float f1 = __uint_as_float(u01 & 0xffff0000u) * linv_r;
            float f2 = __uint_as_float(u23 << 16) * linv_r;
            float f3 = __uint_as_float(u23 & 0xffff0000u) * linv_r;
            *reinterpret_cast<float4*>(attn_row + kvbase + t * 64 + colbase + lgi * 8) =
                (float4){f0, f1, f2, f3};
        }
    }

    // ---- scale O partials, combine across waves ----
#pragma unroll
    for (int c2 = 0; c2 < 4; ++c2)
#pragma unroll
        for (int j = 0; j < 4; ++j)
            olds[wid][lgi * 4 + j][c2 * 16 + lr] = o[c2][j] * ltot[j];
    __syncthreads();

    const int r  = tid >> 4;  // 0..15
    const int c4 = tid & 15;  // 0..15 (float4 column)
    float s0 = 0.f, s1 = 0.f, s2 = 0.f, s3 = 0.f;
#pragma unroll
    for (int w = 0; w < 4; ++w) {
        s0 += olds[w][r][c4 * 4 + 0];
        s1 += olds[w][r][c4 * 4 + 1];
        s2 += olds[w][r][c4 * 4 + 2];
        s3 += olds[w][r][c4 * 4 + 3];
    }
    float* ob = out + (size_t)bh * SEQ * DIM + (size_t)(row16 + r) * DIM + c4 * 4;
    *reinterpret_cast<float4*>(ob) = (float4){s0, s1, s2, s3};
}

extern "C" void kernel_launch(void* const* d_in, const int* in_sizes, int n_in,
                              void* d_out, int out_size, void* d_ws, size_t ws_size,
                              hipStream_t stream) {
    const float* q   = (const float*)d_in[0];
    const float* k   = (const float*)d_in[1];
    const float* v   = (const float*)d_in[2];
    const int*   adj = (const int*)d_in[3];

    float* out  = (float*)d_out;                   // [32,1024,64]
    float* attn = out + (size_t)A_TOT * SEQ * DIM; // [32,1024,1024]

    __hip_bfloat16* qb = (__hip_bfloat16*)d_ws;
    __hip_bfloat16* kb = qb + (size_t)A_TOT * SEQ * DIM;
    __hip_bfloat16* vt = kb + (size_t)A_TOT * SEQ * DIM;

    const int n = A_TOT * SEQ * DIM;  // 2,097,152
    cast_bf16_kernel<<<n / (4 * 256), 256, 0, stream>>>(q, qb, n);
    cast_bf16_kernel<<<n / (4 * 256), 256, 0, stream>>>(k, kb, n);
    transpose_v_kernel<<<dim3(SEQ / 64, A_TOT), 256, 0, stream>>>(v, vt);
    graph_attn_kernel<<<dim3(SEQ / 16, A_TOT), 256, 0, stream>>>(qb, kb, vt, adj, out, attn);
}

// Round 8
// 104.537 us; speedup vs baseline: 1.2842x; 1.0340x over previous
//
#include <hip/hip_runtime.h>
#include <hip/hip_bf16.h>

#define A_TOT 32
#define SEQ 1024
#define DIM 64

typedef __attribute__((ext_vector_type(8))) short short8;
typedef __attribute__((ext_vector_type(4))) float f32x4;

static __device__ __forceinline__ unsigned pack2bf(float a, float b) {
    union { __hip_bfloat16 h[2]; unsigned u; } x;
    x.h[0] = __float2bfloat16(a);
    x.h[1] = __float2bfloat16(b);
    return x.u;
}

// ---------------- cast fp32 -> bf16 ----------------
__global__ void cast_bf16_kernel(const float* __restrict__ src,
                                 __hip_bfloat16* __restrict__ dst, int n) {
    int i = (blockIdx.x * blockDim.x + threadIdx.x) * 4;
    if (i >= n) return;
    float4 f = *reinterpret_cast<const float4*>(src + i);
    union { __hip_bfloat16 h[4]; ushort4 u; } cv;
    cv.h[0] = __float2bfloat16(f.x);
    cv.h[1] = __float2bfloat16(f.y);
    cv.h[2] = __float2bfloat16(f.z);
    cv.h[3] = __float2bfloat16(f.w);
    *reinterpret_cast<ushort4*>(dst + i) = cv.u;
}

// ---------------- transpose+cast v [bh][n][d] -> vt [bh][d][n] ----------------
__global__ void transpose_v_kernel(const float* __restrict__ v,
                                   __hip_bfloat16* __restrict__ vt) {
    __shared__ __hip_bfloat16 tile[64][65];
    int bh = blockIdx.y;
    int n0 = blockIdx.x * 64;
    const float* vsrc = v + ((size_t)bh * SEQ + n0) * DIM;
    for (int e = threadIdx.x; e < 64 * 64; e += 256) {
        int i = e >> 6;
        int d = e & 63;
        tile[i][d] = __float2bfloat16(vsrc[(size_t)i * DIM + d]);
    }
    __syncthreads();
    __hip_bfloat16* vdst = vt + (size_t)bh * DIM * SEQ + n0;
    for (int e = threadIdx.x; e < 64 * 64; e += 256) {
        int d = e >> 6;
        int i = e & 63;
        vdst[(size_t)d * SEQ + i] = tile[i][d];
    }
}

// ---------------- fused masked attention, split-KV, K-permuted ----------------
// grid: (64 row-blocks of 16 rows, 32 bh), block 256 (4 waves).
// Wave w owns rows [rb*16,+16) x KV cols [w*256,+256).
// K rows loaded in permuted order so QK^T (swapped, mfma(K,Q)) output lands
// directly in PV A-fragment ownership (no LDS P staging).
// Round 8: explicit within-tile load batching — all 8 K loads + 4 adj loads
// issued back-to-back before compute (amortizes L2/L3 latency); V loads
// batched per tile; attn stores folded into the PV t-loop.
__launch_bounds__(256)
__global__ void graph_attn_kernel(const __hip_bfloat16* __restrict__ qb,
                                  const __hip_bfloat16* __restrict__ kb,
                                  const __hip_bfloat16* __restrict__ vt,
                                  const int* __restrict__ adj,
                                  float* __restrict__ out,    // [32,1024,64]
                                  float* __restrict__ attn) { // [32,1024,1024]
    __shared__ float olds[4][16][68];      // O partial combine (17408 B)
    __shared__ float part[4][4][16];       // per-wave per-lgi row partials
    __shared__ float lsum_sh[4][16];       // per-wave row sums

    const int bh    = blockIdx.y;
    const int rb    = blockIdx.x;
    const int batch = bh & 3;           // a_idx = h*4 + batch
    const int tid   = threadIdx.x;
    const int wid   = tid >> 6;
    const int lane  = tid & 63;
    const int lr    = lane & 15;        // query row within the 16-row tile
    const int lgi   = lane >> 4;        // k-group / reg-group
    const int row16 = rb * 16;
    const int kvbase = wid * 256;

    // Q fragments: lane holds Q[row16+lr][lgi*8 .. +8) per 32-wide k-step
    const __hip_bfloat16* qrow = qb + ((size_t)bh * SEQ + row16 + lr) * DIM + lgi * 8;
    const short8 qf0 = *reinterpret_cast<const short8*>(qrow);
    const short8 qf1 = *reinterpret_cast<const short8*>(qrow + 32);

    const int* adjrow = adj + (size_t)batch * SEQ * SEQ + (size_t)(row16 + lr) * SEQ;
    const __hip_bfloat16* kbh = kb + (size_t)bh * SEQ * DIM;

    // loader-role row permutation constant for this lane
    const int kperm = (lr >> 2) * 8 + (lr & 3);

    float lp = 0.f;         // lane partial sum of exp over its owned columns
    unsigned p_pk[4][4][2]; // packed unnormalized p: [t][c][pair]

    // ---- Phase A: S = K.Q^T (swapped, K-permuted), p_un = exp -> regs ----
#pragma unroll
    for (int t = 0; t < 4; ++t) {
        const int n0 = kvbase + t * 64;
        // batch-issue all 8 K loads + 4 adj loads for this tile
        short8 kf[4][2];
#pragma unroll
        for (int c = 0; c < 4; ++c) {
            const int colbase = (c >> 1) * 32 + (c & 1) * 4;
            const __hip_bfloat16* krow =
                kbh + (size_t)(n0 + colbase + kperm) * DIM + lgi * 8;
            kf[c][0] = *reinterpret_cast<const short8*>(krow);
            kf[c][1] = *reinterpret_cast<const short8*>(krow + 32);
        }
        int4 av4[4];
#pragma unroll
        for (int c = 0; c < 4; ++c) {
            const int colbase = (c >> 1) * 32 + (c & 1) * 4;
            av4[c] = *reinterpret_cast<const int4*>(adjrow + n0 + colbase + lgi * 8);
        }
        // compute: 4 x (2 MFMA + mask + exp + pack)
#pragma unroll
        for (int c = 0; c < 4; ++c) {
            f32x4 acc = {0.f, 0.f, 0.f, 0.f};
            acc = __builtin_amdgcn_mfma_f32_16x16x32_bf16(kf[c][0], qf0, acc, 0, 0, 0);
            acc = __builtin_amdgcn_mfma_f32_16x16x32_bf16(kf[c][1], qf1, acc, 0, 0, 0);
            // acc[j] = S[q=row16+lr][kv = n0 + colbase + lgi*8 + j]
            float p0 = (av4[c].x > 0) ? __expf(acc[0] * 0.125f) : 0.f;
            float p1 = (av4[c].y > 0) ? __expf(acc[1] * 0.125f) : 0.f;
            float p2 = (av4[c].z > 0) ? __expf(acc[2] * 0.125f) : 0.f;
            float p3 = (av4[c].w > 0) ? __expf(acc[3] * 0.125f) : 0.f;
            lp += (p0 + p1) + (p2 + p3);
            p_pk[t][c][0] = pack2bf(p0, p1);
            p_pk[t][c][1] = pack2bf(p2, p3);
        }
    }

    // ---- Phase B: wave-local row sums via LDS, then cross-wave combine ----
    part[wid][lgi][lr] = lp;
    asm volatile("" ::: "memory");
    if (lane < 16) {
        lsum_sh[wid][lane] = part[wid][0][lane] + part[wid][1][lane] +
                             part[wid][2][lane] + part[wid][3][lane];
    }
    __syncthreads();

    float ltot[4];
#pragma unroll
    for (int j = 0; j < 4; ++j) {
        const int row = lgi * 4 + j;
        float s = lsum_sh[0][row] + lsum_sh[1][row] + lsum_sh[2][row] + lsum_sh[3][row];
        ltot[j] = 1.0f / (s + 1e-37f);
    }
    float lrt = lsum_sh[0][lr] + lsum_sh[1][lr] + lsum_sh[2][lr] + lsum_sh[3][lr];
    const float linv_r = 1.0f / (lrt + 1e-37f);

    // ---- Phase C: PV (register-concat P fragments, batched V loads)
    //      + attn stores folded in (overlap next tile's load latency) ----
    f32x4 o[4];
#pragma unroll
    for (int c = 0; c < 4; ++c) o[c] = (f32x4){0.f, 0.f, 0.f, 0.f};

    float* attn_row = attn + (size_t)bh * SEQ * SEQ + (size_t)(row16 + lr) * SEQ;

#pragma unroll
    for (int t = 0; t < 4; ++t) {
        const int n0 = kvbase + t * 64;
        // batch-issue all 8 V loads for this tile
        short8 vf[4][2];
#pragma unroll
        for (int c2 = 0; c2 < 4; ++c2) {
            const __hip_bfloat16* vrow =
                vt + ((size_t)bh * DIM + c2 * 16 + lr) * SEQ + n0 + lgi * 8;
            vf[c2][0] = *reinterpret_cast<const short8*>(vrow);
            vf[c2][1] = *reinterpret_cast<const short8*>(vrow + 32);
        }
        union { unsigned u[4]; short8 s; } pf0, pf1;
        pf0.u[0] = p_pk[t][0][0]; pf0.u[1] = p_pk[t][0][1];
        pf0.u[2] = p_pk[t][1][0]; pf0.u[3] = p_pk[t][1][1];
        pf1.u[0] = p_pk[t][2][0]; pf1.u[1] = p_pk[t][2][1];
        pf1.u[2] = p_pk[t][3][0]; pf1.u[3] = p_pk[t][3][1];
#pragma unroll
        for (int c2 = 0; c2 < 4; ++c2) {
            o[c2] = __builtin_amdgcn_mfma_f32_16x16x32_bf16(pf0.s, vf[c2][0], o[c2], 0, 0, 0);
            o[c2] = __builtin_amdgcn_mfma_f32_16x16x32_bf16(pf1.s, vf[c2][1], o[c2], 0, 0, 0);
        }
        // attn writes for tile t (normalized, unpacked from regs)
#pragma unroll
        for (int c = 0; c < 4; ++c) {
            const int colbase = (c >> 1) * 32 + (c & 1) * 4;
            const unsigned u01 = p_pk[t][c][0];
            const unsigned u23 = p_pk[t][c][1];
            float f0 = __uint_as_float(u01 << 16) * linv_r;
            float f1 = __uint_as_float(u01 & 0xffff0000u) * linv_r;
            float f2 = __uint_as_float(u23 << 16) * linv_r;
            float f3 = __uint_as_float(u23 & 0xffff0000u) * linv_r;
            *reinterpret_cast<float4*>(attn_row + n0 + colbase + lgi * 8) =
                (float4){f0, f1, f2, f3};
        }
    }

    // ---- scale O partials, combine across waves ----
#pragma unroll
    for (int c2 = 0; c2 < 4; ++c2)
#pragma unroll
        for (int j = 0; j < 4; ++j)
            olds[wid][lgi * 4 + j][c2 * 16 + lr] = o[c2][j] * ltot[j];
    __syncthreads();

    const int r  = tid >> 4;  // 0..15
    const int c4 = tid & 15;  // 0..15 (float4 column)
    float s0 = 0.f, s1 = 0.f, s2 = 0.f, s3 = 0.f;
#pragma unroll
    for (int w = 0; w < 4; ++w) {
        s0 += olds[w][r][c4 * 4 + 0];
        s1 += olds[w][r][c4 * 4 + 1];
        s2 += olds[w][r][c4 * 4 + 2];
        s3 += olds[w][r][c4 * 4 + 3];
    }
    float* ob = out + (size_t)bh * SEQ * DIM + (size_t)(row16 + r) * DIM + c4 * 4;
    *reinterpret_cast<float4*>(ob) = (float4){s0, s1, s2, s3};
}

extern "C" void kernel_launch(void* const* d_in, const int* in_sizes, int n_in,
                              void* d_out, int out_size, void* d_ws, size_t ws_size,
                              hipStream_t stream) {
    const float* q   = (const float*)d_in[0];
    const float* k   = (const float*)d_in[1];
    const float* v   = (const float*)d_in[2];
    const int*   adj = (const int*)d_in[3];

    float* out  = (float*)d_out;                   // [32,1024,64]
    float* attn = out + (size_t)A_TOT * SEQ * DIM; // [32,1024,1024]

    __hip_bfloat16* qb = (__hip_bfloat16*)d_ws;
    __hip_bfloat16* kb = qb + (size_t)A_TOT * SEQ * DIM;
    __hip_bfloat16* vt = kb + (size_t)A_TOT * SEQ * DIM;

    const int n = A_TOT * SEQ * DIM;  // 2,097,152
    cast_bf16_kernel<<<n / (4 * 256), 256, 0, stream>>>(q, qb, n);
    cast_bf16_kernel<<<n / (4 * 256), 256, 0, stream>>>(k, kb, n);
    transpose_v_kernel<<<dim3(SEQ / 64, A_TOT), 256, 0, stream>>>(v, vt);
    graph_attn_kernel<<<dim3(SEQ / 16, A_TOT), 256, 0, stream>>>(qb, kb, vt, adj, out, attn);
}